// Round 3
// baseline (211207.642 us; speedup 1.0000x reference)
//
#include <hip/hip_runtime.h>
#include <math.h>

// B=128, E=512, D=512, V=275, HW=24 -> P=576, T=300
static constexpr int Bn  = 128;
static constexpr int En  = 512;
static constexpr int Dn  = 512;
static constexpr int Vn  = 275;
static constexpr int Pn  = 576;
static constexpr int Tn  = 300;
static constexpr int TM1 = 299;

static constexpr int NBLK  = 512;            // persistent grid (2/CU; capacity 3/CU = 768)
static constexpr int NWAVE = NBLK * 4;       // 2048 waves

typedef unsigned short ushort_t;
typedef unsigned int uint_t;

__device__ __forceinline__ float fast_tanh(float x) {
    float e2 = __expf(2.0f * x);
    return 1.0f - 2.0f / (e2 + 1.0f);
}
__device__ __forceinline__ float sigmoidf_(float x) {
    return 1.0f / (1.0f + __expf(-x));
}
__device__ __forceinline__ float wave_reduce(float v) {
#pragma unroll
    for (int o = 32; o > 0; o >>= 1) v += __shfl_xor(v, o, 64);
    return v;
}
__device__ __forceinline__ ushort_t f2b(float x) {      // fp32 -> bf16 RNE
    uint_t u = __float_as_uint(x);
    u = (u + 0x7fffu + ((u >> 16) & 1u)) >> 16;
    return (ushort_t)u;
}
__device__ __forceinline__ float b2f(ushort_t u) {
    return __uint_as_float(((uint_t)u) << 16);
}
__device__ __forceinline__ void unpack8(uint4 q, float* f) {  // 8 bf16 (LE pairs)
    f[0] = __uint_as_float(q.x << 16); f[1] = __uint_as_float(q.x & 0xffff0000u);
    f[2] = __uint_as_float(q.y << 16); f[3] = __uint_as_float(q.y & 0xffff0000u);
    f[4] = __uint_as_float(q.z << 16); f[5] = __uint_as_float(q.z & 0xffff0000u);
    f[6] = __uint_as_float(q.w << 16); f[7] = __uint_as_float(q.w & 0xffff0000u);
}

// ---------------- one-time kernels ----------------

__global__ void mean_kernel(const float* __restrict__ feats, float* __restrict__ mean) {
    int w = blockIdx.x * 4 + (threadIdx.x >> 6);
    int lane = threadIdx.x & 63;
    const float* row = feats + (size_t)w * Pn;
    float s = 0.f;
#pragma unroll
    for (int i = 0; i < 9; i++) s += row[lane + i * 64];
    s = wave_reduce(s);
    if (lane == 0) mean[w] = s * (1.0f / Pn);
}

__global__ void init_kernel(const float* __restrict__ mean,
                            const float* __restrict__ ihw, const float* __restrict__ ihb,
                            const float* __restrict__ icw, const float* __restrict__ icb,
                            float* __restrict__ h, float* __restrict__ c) {
    int b = blockIdx.x; int d = threadIdx.x;
    const float* m = mean + b * En;
    float ah = ihb[d], ac = icb[d];
#pragma unroll 8
    for (int e = 0; e < En; e++) {
        float mv = m[e];
        ah += mv * ihw[e * Dn + d];
        ac += mv * icw[e * Dn + d];
    }
    h[b * Dn + d] = ah;
    c[b * Dn + d] = ac;
}

// Ws[b,p,d] -> bf16; 8 p per block to amortize the Ww read 8x.
__global__ void ws_kernel(const float* __restrict__ feats, const float* __restrict__ Ww,
                          const float* __restrict__ Wb, ushort_t* __restrict__ WsH) {
    int p0 = blockIdx.x * 8, b = blockIdx.y, d = threadIdx.x;  // 512 threads
    float acc[8];
    float bias = Wb[d];
#pragma unroll
    for (int k = 0; k < 8; k++) acc[k] = bias;
    const float* fbase = feats + (size_t)b * En * Pn + p0;
#pragma unroll 4
    for (int e = 0; e < En; e++) {
        float w = Ww[e * Dn + d];
        const float4* fp = (const float4*)(fbase + (size_t)e * Pn);
        float4 fA = fp[0], fB = fp[1];
        acc[0] += fA.x * w; acc[1] += fA.y * w; acc[2] += fA.z * w; acc[3] += fA.w * w;
        acc[4] += fB.x * w; acc[5] += fB.y * w; acc[6] += fB.z * w; acc[7] += fB.w * w;
    }
#pragma unroll
    for (int k = 0; k < 8; k++)
        WsH[((size_t)b * Pn + p0 + k) * Dn + d] = f2b(acc[k]);
}

__global__ void declen_kernel(const int* __restrict__ lengths, float* __restrict__ out_declen) {
    int b = threadIdx.x;
    if (b < Bn) out_declen[b] = (float)(lengths[b] - 1);
}

__global__ void cvt_kernel(const float* __restrict__ src, ushort_t* __restrict__ dst, int n) {
    int idx = blockIdx.x * 256 + threadIdx.x;
    if (idx < n) dst[idx] = f2b(src[idx]);
}

__global__ void cvtT_kernel(const float* __restrict__ src, ushort_t* __restrict__ dst,
                            int rows, int cols) {
    int idx = blockIdx.x * 256 + threadIdx.x;
    if (idx >= rows * cols) return;
    int r = idx / cols, c = idx - r * cols;
    dst[(size_t)c * rows + r] = f2b(src[idx]);
}

// ---------------- grid barrier (two-level, agent scope) ----------------
// bar layout (ints): [g*32] group counters (16 groups), [512] root, [544] generation
__device__ __forceinline__ void gridbar(int* bar) {
    __threadfence();          // release: make this thread's writes agent-visible
    __syncthreads();
    if (threadIdx.x == 0) {
        int* gcnt = bar + ((blockIdx.x >> 5) << 5);
        int* root = bar + 512;
        int* gen  = bar + 544;
        int g = __hip_atomic_load(gen, __ATOMIC_RELAXED, __HIP_MEMORY_SCOPE_AGENT);
        bool done = false;
        if (__hip_atomic_fetch_add(gcnt, 1, __ATOMIC_ACQ_REL, __HIP_MEMORY_SCOPE_AGENT) == 31) {
            __hip_atomic_store(gcnt, 0, __ATOMIC_RELAXED, __HIP_MEMORY_SCOPE_AGENT);
            if (__hip_atomic_fetch_add(root, 1, __ATOMIC_ACQ_REL, __HIP_MEMORY_SCOPE_AGENT) == 15) {
                __hip_atomic_store(root, 0, __ATOMIC_RELAXED, __HIP_MEMORY_SCOPE_AGENT);
                __hip_atomic_fetch_add(gen, 1, __ATOMIC_RELEASE, __HIP_MEMORY_SCOPE_AGENT);
                done = true;
            }
        }
        if (!done) {
            unsigned spins = 0;
            while (__hip_atomic_load(gen, __ATOMIC_ACQUIRE, __HIP_MEMORY_SCOPE_AGENT) == g) {
                __builtin_amdgcn_s_sleep(1);
                if (++spins > 400000000u) break;   // break deadlock into wrong-answer, not hang
            }
        }
    }
    __syncthreads();
    __threadfence();          // acquire: invalidate stale cached data for all threads
}

// ---------------- the persistent step kernel ----------------

__global__ __launch_bounds__(256, 3) void mega_kernel(
        const ushort_t* __restrict__ WsH, const ushort_t* __restrict__ featsH,
        const ushort_t* __restrict__ wihH, const ushort_t* __restrict__ whhH,
        const ushort_t* __restrict__ UwTh, const ushort_t* __restrict__ fbwTh,
        const ushort_t* __restrict__ fcwTh,
        const float* __restrict__ Ub, const float* __restrict__ fbb,
        const float* __restrict__ fcb,
        const float* __restrict__ vw, const float* __restrict__ vb,
        const float* __restrict__ bih, const float* __restrict__ bhh,
        const float* __restrict__ emb, const int* __restrict__ captions,
        const int* __restrict__ lengths,
        float* __restrict__ hA, float* __restrict__ hB, float* __restrict__ cbuf,
        float* __restrict__ hU, float* __restrict__ gate, float* __restrict__ xctx,
        float* __restrict__ esc, float* __restrict__ alpha,
        float* __restrict__ out_preds, float* __restrict__ out_alphas,
        int* __restrict__ bar) {
    const int tid  = threadIdx.x;
    const int lane = tid & 63;
    const int gwid = blockIdx.x * 4 + (tid >> 6);   // [0, 2048)

    __shared__ float sb[Pn];
    __shared__ float red2[8];

    // constants hoisted across all steps
    const float4* v4 = (const float4*)vw;
    const float4 v0 = v4[2 * lane], v1 = v4[2 * lane + 1];
    const float vbv = vb[0];

#pragma unroll 1
    for (int tau = 0; tau <= TM1; tau++) {
        const float* hcur = (tau & 1) ? hB : hA;
        float* hnext = (tau & 1) ? hA : hB;

        // ---------- Phase A: hU = h@U+b ; gate = sig(h@fb+b) ; preds(t=tau-1) = h@fc+b ----------
        {
            const int bg = gwid & 31;                 // constant across iters
            const float4* h4 = (const float4*)hcur;
            float4 hv[4][2];
#pragma unroll
            for (int i = 0; i < 4; i++) {
                int base = ((bg << 2) + i) * 128 + 2 * lane;
                hv[i][0] = h4[base]; hv[i][1] = h4[base + 1];
            }
#pragma unroll 1
            for (int it = 0; it < 11; it++) {
                int t = it * NWAVE + gwid;
                if (t >= 32 * 650) break;
                int jp = t >> 5;
#pragma unroll
                for (int jj = 0; jj < 2; jj++) {
                    int j = jp * 2 + jj;
                    if (j >= 1299) continue;
                    if (j >= 1024 && tau == 0) continue;
                    const ushort_t* row;
                    if (j < 512) row = UwTh + ((size_t)j << 9);
                    else if (j < 1024) row = fbwTh + ((size_t)(j - 512) << 9);
                    else row = fcwTh + ((size_t)(j - 1024) << 9);
                    uint4 q = *(const uint4*)(row + 8 * lane);
                    float w8[8]; unpack8(q, w8);
                    float a[4];
#pragma unroll
                    for (int i = 0; i < 4; i++) {
                        a[i] = hv[i][0].x * w8[0] + hv[i][0].y * w8[1] + hv[i][0].z * w8[2] + hv[i][0].w * w8[3]
                             + hv[i][1].x * w8[4] + hv[i][1].y * w8[5] + hv[i][1].z * w8[6] + hv[i][1].w * w8[7];
                    }
#pragma unroll
                    for (int o = 32; o > 0; o >>= 1) {
#pragma unroll
                        for (int i = 0; i < 4; i++) a[i] += __shfl_xor(a[i], o, 64);
                    }
                    if (lane == 0) {
                        if (j < 512) {
                            float bias = Ub[j];
#pragma unroll
                            for (int i = 0; i < 4; i++) hU[((bg << 2) + i) * Dn + j] = a[i] + bias;
                        } else if (j < 1024) {
                            int e = j - 512;
                            float bias = fbb[e];
#pragma unroll
                            for (int i = 0; i < 4; i++) gate[((bg << 2) + i) * En + e] = sigmoidf_(a[i] + bias);
                        } else {
                            int v = j - 1024;
                            int tt = tau - 1;
                            float bias = fcb[v];
#pragma unroll
                            for (int i = 0; i < 4; i++) {
                                int b = (bg << 2) + i;
                                int dec = lengths[b] - 1;
                                out_preds[((size_t)b * TM1 + tt) * Vn + v] = (tt < dec) ? (a[i] + bias) : 0.f;
                            }
                        }
                    }
                }
            }
        }
        if (tau == TM1) break;
        gridbar(bar);

        // ---------- Phase B: esc[b,p] = v . tanh(Ws[b,p,:] + hU[b,:]) + vb ----------
        {
            const int b = gwid & 127;                 // constant across iters
            const float4* hu4 = (const float4*)(hU + (b << 9));
            const float4 h0 = hu4[2 * lane], h1 = hu4[2 * lane + 1];
            const ushort_t* wsb = WsH + ((size_t)b * Pn << 9);
            int p = (0 * NWAVE + gwid) >> 7;
            uint4 q = *(const uint4*)(wsb + ((size_t)p << 9) + 8 * lane);
#pragma unroll 1
            for (int it = 0; it < 36; it++) {
                uint4 qn;
                if (it < 35) {
                    int pn2 = ((it + 1) * NWAVE + gwid) >> 7;
                    qn = *(const uint4*)(wsb + ((size_t)pn2 << 9) + 8 * lane);
                }
                float w8[8]; unpack8(q, w8);
                float acc;
                acc  = fast_tanh(w8[0] + h0.x) * v0.x;
                acc += fast_tanh(w8[1] + h0.y) * v0.y;
                acc += fast_tanh(w8[2] + h0.z) * v0.z;
                acc += fast_tanh(w8[3] + h0.w) * v0.w;
                acc += fast_tanh(w8[4] + h1.x) * v1.x;
                acc += fast_tanh(w8[5] + h1.y) * v1.y;
                acc += fast_tanh(w8[6] + h1.z) * v1.z;
                acc += fast_tanh(w8[7] + h1.w) * v1.w;
                acc = wave_reduce(acc);
                if (lane == 0) esc[b * Pn + p] = acc + vbv;
                p = ((it + 1) * NWAVE + gwid) >> 7;
                q = qn;
            }
        }
        gridbar(bar);

        // ---------- Phase C: softmax over p per b (blocks 0..127) ----------
        if (blockIdx.x < Bn) {
            int b = blockIdx.x;
            float v2 = esc[b * Pn + tid];
            float v3 = esc[b * Pn + 256 + tid];
            float v4x = (tid < 64) ? esc[b * Pn + 512 + tid] : -1e30f;
            sb[tid] = v2; sb[256 + tid] = v3;
            if (tid < 64) sb[512 + tid] = v4x;
            float m = fmaxf(fmaxf(v2, v3), v4x);
#pragma unroll
            for (int o = 32; o > 0; o >>= 1) m = fmaxf(m, __shfl_xor(m, o, 64));
            if (lane == 0) red2[tid >> 6] = m;
            __syncthreads();
            m = fmaxf(fmaxf(red2[0], red2[1]), fmaxf(red2[2], red2[3]));
            float e0 = __expf(sb[tid] - m);
            float e1 = __expf(sb[256 + tid] - m);
            float e2x = (tid < 64) ? __expf(sb[512 + tid] - m) : 0.f;
            float s = e0 + e1 + e2x;
#pragma unroll
            for (int o = 32; o > 0; o >>= 1) s += __shfl_xor(s, o, 64);
            if (lane == 0) red2[4 + (tid >> 6)] = s;
            __syncthreads();
            s = red2[4] + red2[5] + red2[6] + red2[7];
            float inv = 1.0f / s;
            int dec = lengths[b] - 1;
            float msk = (tau < dec) ? 1.f : 0.f;
            float* ar = alpha + b * Pn;
            float* oar = out_alphas + ((size_t)b * TM1 + tau) * Pn;
            ar[tid] = e0 * inv;            oar[tid] = e0 * inv * msk;
            ar[256 + tid] = e1 * inv;      oar[256 + tid] = e1 * inv * msk;
            if (tid < 64) { ar[512 + tid] = e2x * inv; oar[512 + tid] = e2x * inv * msk; }
        }
        gridbar(bar);

        // ---------- Phase D: xctx[b,e] = gate[b,e] * (alpha[b,:] . feats[b,e,:]) ----------
        {
            const int b = gwid & 127;                 // constant across iters
            const float4* a4 = (const float4*)(alpha + b * Pn);
            const float4 a0 = a4[2 * lane], a1 = a4[2 * lane + 1];
            const float at = alpha[b * Pn + 512 + lane];
            const ushort_t* fb2 = featsH + (size_t)b * En * Pn;
            int e = (0 * NWAVE + gwid) >> 7;
            uint4 q = *(const uint4*)(fb2 + (size_t)e * Pn + 8 * lane);
            ushort_t qt = fb2[(size_t)e * Pn + 512 + lane];
#pragma unroll 1
            for (int it = 0; it < 32; it++) {
                uint4 qn; ushort_t qtn;
                if (it < 31) {
                    int en = ((it + 1) * NWAVE + gwid) >> 7;
                    qn = *(const uint4*)(fb2 + (size_t)en * Pn + 8 * lane);
                    qtn = fb2[(size_t)en * Pn + 512 + lane];
                }
                float w8[8]; unpack8(q, w8);
                float s;
                s  = w8[0] * a0.x + w8[1] * a0.y + w8[2] * a0.z + w8[3] * a0.w;
                s += w8[4] * a1.x + w8[5] * a1.y + w8[6] * a1.z + w8[7] * a1.w;
                s += b2f(qt) * at;
                s = wave_reduce(s);
                if (lane == 0) xctx[(b << 9) + e] = gate[(b << 9) + e] * s;
                e = ((it + 1) * NWAVE + gwid) >> 7;
                q = qn; qt = qtn;
            }
        }
        gridbar(bar);

        // ---------- Phase E: LSTM gates + pointwise ----------
        {
            const int bg = gwid & 31;                 // constant across iters
            float4 u[4][6];
#pragma unroll
            for (int i = 0; i < 4; i++) {
                int b = (bg << 2) + i;
                int tok = captions[b * Tn + tau];
                const float4* e4 = (const float4*)(emb + (size_t)tok * Dn);
                const float4* x4 = (const float4*)(xctx + (b << 9));
                const float4* h4 = (const float4*)(hcur + (b << 9));
                u[i][0] = e4[2 * lane]; u[i][1] = e4[2 * lane + 1];
                u[i][2] = x4[2 * lane]; u[i][3] = x4[2 * lane + 1];
                u[i][4] = h4[2 * lane]; u[i][5] = h4[2 * lane + 1];
            }
#pragma unroll 1
            for (int it = 0; it < 8; it++) {
                int d = (it * NWAVE + gwid) >> 5;
                float acc[4][4];
#pragma unroll
                for (int g = 0; g < 4; g++) {
                    int j = (g << 9) + d;
                    const ushort_t* wi = wihH + ((size_t)j << 10);
                    const ushort_t* wh = whhH + ((size_t)j << 9);
                    uint4 q0 = *(const uint4*)(wi + 8 * lane);
                    uint4 q1 = *(const uint4*)(wi + 512 + 8 * lane);
                    uint4 q2 = *(const uint4*)(wh + 8 * lane);
                    float wa[8], wb2[8], wc[8];
                    unpack8(q0, wa); unpack8(q1, wb2); unpack8(q2, wc);
#pragma unroll
                    for (int i = 0; i < 4; i++) {
                        float s;
                        s  = u[i][0].x * wa[0] + u[i][0].y * wa[1] + u[i][0].z * wa[2] + u[i][0].w * wa[3];
                        s += u[i][1].x * wa[4] + u[i][1].y * wa[5] + u[i][1].z * wa[6] + u[i][1].w * wa[7];
                        s += u[i][2].x * wb2[0] + u[i][2].y * wb2[1] + u[i][2].z * wb2[2] + u[i][2].w * wb2[3];
                        s += u[i][3].x * wb2[4] + u[i][3].y * wb2[5] + u[i][3].z * wb2[6] + u[i][3].w * wb2[7];
                        s += u[i][4].x * wc[0] + u[i][4].y * wc[1] + u[i][4].z * wc[2] + u[i][4].w * wc[3];
                        s += u[i][5].x * wc[4] + u[i][5].y * wc[5] + u[i][5].z * wc[6] + u[i][5].w * wc[7];
                        acc[g][i] = s;
                    }
                }
#pragma unroll
                for (int o = 32; o > 0; o >>= 1) {
#pragma unroll
                    for (int g = 0; g < 4; g++)
#pragma unroll
                        for (int i = 0; i < 4; i++) acc[g][i] += __shfl_xor(acc[g][i], o, 64);
                }
                if (lane == 0) {
                    float bi = bih[d] + bhh[d];
                    float bf = bih[512 + d] + bhh[512 + d];
                    float bgg = bih[1024 + d] + bhh[1024 + d];
                    float bo = bih[1536 + d] + bhh[1536 + d];
#pragma unroll
                    for (int i = 0; i < 4; i++) {
                        int b = (bg << 2) + i;
                        float ig = sigmoidf_(acc[0][i] + bi);
                        float fg = sigmoidf_(acc[1][i] + bf);
                        float gg = fast_tanh(acc[2][i] + bgg);
                        float og = sigmoidf_(acc[3][i] + bo);
                        float cn = fg * cbuf[(b << 9) + d] + ig * gg;
                        cbuf[(b << 9) + d] = cn;
                        hnext[(b << 9) + d] = og * fast_tanh(cn);
                    }
                }
            }
        }
        gridbar(bar);
    }
}

extern "C" void kernel_launch(void* const* d_in, const int* in_sizes, int n_in,
                              void* d_out, int out_size, void* d_ws, size_t ws_size,
                              hipStream_t stream) {
    const float* feats    = (const float*)d_in[0];
    const int*   captions = (const int*)d_in[1];
    const int*   lengths  = (const int*)d_in[2];
    const float* U_w      = (const float*)d_in[3];
    const float* U_b      = (const float*)d_in[4];
    const float* W_w      = (const float*)d_in[5];
    const float* W_b      = (const float*)d_in[6];
    const float* v_w      = (const float*)d_in[7];
    const float* v_b      = (const float*)d_in[8];
    const float* init_h_w = (const float*)d_in[9];
    const float* init_h_b = (const float*)d_in[10];
    const float* init_c_w = (const float*)d_in[11];
    const float* init_c_b = (const float*)d_in[12];
    const float* f_beta_w = (const float*)d_in[13];
    const float* f_beta_b = (const float*)d_in[14];
    const float* fc_w     = (const float*)d_in[15];
    const float* fc_b     = (const float*)d_in[16];
    const float* emb      = (const float*)d_in[17];
    const float* lstm_w_ih = (const float*)d_in[18];
    const float* lstm_w_hh = (const float*)d_in[19];
    const float* lstm_b_ih = (const float*)d_in[20];
    const float* lstm_b_hh = (const float*)d_in[21];

    char* base = (char*)d_ws;
    size_t off = 0;
    int* bar = (int*)(base + off); off += 8192;
    ushort_t* WsH    = (ushort_t*)(base + off); off += (size_t)Bn * Pn * Dn * 2;
    ushort_t* featsH = (ushort_t*)(base + off); off += (size_t)Bn * En * Pn * 2;
    ushort_t* wihH   = (ushort_t*)(base + off); off += (size_t)4 * Dn * (Dn + En) * 2;
    ushort_t* whhH   = (ushort_t*)(base + off); off += (size_t)4 * Dn * Dn * 2;
    ushort_t* UwTh   = (ushort_t*)(base + off); off += (size_t)Dn * Dn * 2;
    ushort_t* fbwTh  = (ushort_t*)(base + off); off += (size_t)En * Dn * 2;
    ushort_t* fcwTh  = (ushort_t*)(base + off); off += (size_t)Vn * Dn * 2 + 512;
    float* mean  = (float*)(base + off); off += (size_t)Bn * En * 4;
    float* hA    = (float*)(base + off); off += (size_t)Bn * Dn * 4;
    float* hB    = (float*)(base + off); off += (size_t)Bn * Dn * 4;
    float* cbuf  = (float*)(base + off); off += (size_t)Bn * Dn * 4;
    float* hU    = (float*)(base + off); off += (size_t)Bn * Dn * 4;
    float* gate  = (float*)(base + off); off += (size_t)Bn * En * 4;
    float* xctx  = (float*)(base + off); off += (size_t)Bn * En * 4;
    float* esc   = (float*)(base + off); off += (size_t)Bn * Pn * 4;
    float* alpha = (float*)(base + off); off += (size_t)Bn * Pn * 4;

    float* out_preds  = (float*)d_out;
    float* out_alphas = out_preds + (size_t)Bn * TM1 * Vn;
    float* out_declen = out_alphas + (size_t)Bn * TM1 * Pn;

    // ---- one-time precompute ----
    hipMemsetAsync(bar, 0, 8192, stream);
    mean_kernel<<<Bn * En / 4, 256, 0, stream>>>(feats, mean);
    init_kernel<<<Bn, 512, 0, stream>>>(mean, init_h_w, init_h_b, init_c_w, init_c_b, hA, cbuf);
    ws_kernel<<<dim3(Pn / 8, Bn), 512, 0, stream>>>(feats, W_w, W_b, WsH);
    declen_kernel<<<1, 128, 0, stream>>>(lengths, out_declen);
    {
        int n = Bn * En * Pn;
        cvt_kernel<<<(n + 255) / 256, 256, 0, stream>>>(feats, featsH, n);
    }
    cvt_kernel<<<(4 * Dn * (Dn + En) + 255) / 256, 256, 0, stream>>>(lstm_w_ih, wihH, 4 * Dn * (Dn + En));
    cvt_kernel<<<(4 * Dn * Dn + 255) / 256, 256, 0, stream>>>(lstm_w_hh, whhH, 4 * Dn * Dn);
    cvtT_kernel<<<(Dn * Dn + 255) / 256, 256, 0, stream>>>(U_w, UwTh, Dn, Dn);
    cvtT_kernel<<<(Dn * En + 255) / 256, 256, 0, stream>>>(f_beta_w, fbwTh, Dn, En);
    cvtT_kernel<<<(Dn * Vn + 255) / 256, 256, 0, stream>>>(fc_w, fcwTh, Dn, Vn);

    // ---- the whole recurrent loop in one persistent kernel ----
    mega_kernel<<<NBLK, 256, 0, stream>>>(
        WsH, featsH, wihH, whhH, UwTh, fbwTh, fcwTh,
        U_b, f_beta_b, fc_b, v_w, v_b, lstm_b_ih, lstm_b_hh,
        emb, captions, lengths,
        hA, hB, cbuf, hU, gate, xctx, esc, alpha,
        out_preds, out_alphas, bar);
}